// Round 11
// baseline (50.531 us; speedup 1.0000x reference)
//
#include <hip/hip_runtime.h>
#include <math.h>

#define B 128
#define E 6
#define IN_DIM 1664
#define H_DIM 512
#define OUT_DIM 618
#define ZD 32
#define K2 544
#define S1 13             // L1 split-K (KPB=4)
#define S23 9             // L2/L3 split-K (8x2kb + 1x1kb z-split)

typedef __attribute__((ext_vector_type(8))) short short8;
typedef __attribute__((ext_vector_type(4))) float f32x4;
union U128 { uint4 u4; short8 s8; ushort us[8]; };

__device__ __forceinline__ ushort f2bf(float f) {   // fp32 -> bf16 RNE
    uint u = __float_as_uint(f);
    u += 0x7fffu + ((u >> 16) & 1u);
    return (ushort)(u >> 16);
}
__device__ __forceinline__ uint pk2(float a, float b) {
    return (uint)f2bf(a) | ((uint)f2bf(b) << 16);
}
__device__ __forceinline__ float elu1(float x) { return x < 0.f ? expm1f(x) : x; }

// MFMA frag math (HW-validated r3-r10):
//  A frag (kb,m): lane l -> row 16m+(l&15), k = 32kb+(l>>4)*8+j
//  B frag (kb,nf): lane l -> col 16nf+(l&15), k = 32kb+(l>>4)*8+j
//  C/D: col = l&15, row = (l>>4)*4 + r

// ---------------------------------------------------------------------------
// init_bias: y1,y2,y3 <- coef-blended biases (all in workspace). Gemms
// atomically accumulate on top; consumers apply elu (mid) or copy out (last).
// ---------------------------------------------------------------------------
__global__ __launch_bounds__(256) void init_bias(
    const float* __restrict__ coef,
    const float* __restrict__ b1, const float* __restrict__ b2,
    const float* __restrict__ b3,
    float* __restrict__ y1, float* __restrict__ y2, float* __restrict__ y3)
{
    const int idx = blockIdx.x * 256 + threadIdx.x;
    if (idx >= B * (2 * H_DIM + OUT_DIM)) return;
    const int b = idx / (2 * H_DIM + OUT_DIM);
    const int o = idx - b * (2 * H_DIM + OUT_DIM);
    float ce[E];
    #pragma unroll
    for (int e = 0; e < E; ++e) ce[e] = coef[b * E + e];
    float v = 0.f;
    if (o < H_DIM) {
        #pragma unroll
        for (int e = 0; e < E; ++e) v = fmaf(ce[e], b1[e * H_DIM + o], v);
        y1[b * H_DIM + o] = v;
    } else if (o < 2 * H_DIM) {
        const int oo = o - H_DIM;
        #pragma unroll
        for (int e = 0; e < E; ++e) v = fmaf(ce[e], b2[e * H_DIM + oo], v);
        y2[b * H_DIM + oo] = v;
    } else {
        const int oo = o - 2 * H_DIM;
        #pragma unroll
        for (int e = 0; e < E; ++e) v = fmaf(ce[e], b3[e * OUT_DIM + oo], v);
        y3[b * OUT_DIM + oo] = v;
    }
}

// ---------------------------------------------------------------------------
// gemm1: L1, block tile 128x32, KPB=4 (24 steps). A-frags from fp32 x*coef
// in-register; W fp32 -> bf16 -> LDS frags (dbuf, 2-step prefetch, 1
// barrier/step). Epilogue: atomicAdd into y1 (bias pre-initialized).
// ---------------------------------------------------------------------------
__global__ __launch_bounds__(256) void gemm1(
    const float* __restrict__ x,     // [B][IN_DIM]
    const float* __restrict__ coef,  // [B][E]
    const float* __restrict__ w,     // [E][IN_DIM][H_DIM]
    float* __restrict__ y1)          // [B][H_DIM] accum
{
    const int tid = threadIdx.x;
    const int l = tid & 63, wv = tid >> 6;
    const int n0 = blockIdx.x * 32, kb0 = blockIdx.y * 4;
    const int tn = tid & 31, tkq = tid >> 5;
    const int lp = ((tkq >> 1) << 4) | (tn & 15);
    const int fI = tn >> 4, j0 = (tkq & 1) << 2;
    const int colW = n0 + tn;
    const int row0 = 32 * wv + (l & 15), row1 = row0 + 16, kq = l >> 4;

    __shared__ ushort bs[2][2][64][8];

    float ce0[E], ce1[E];
    #pragma unroll
    for (int e = 0; e < E; ++e) {
        ce0[e] = coef[row0 * E + e];
        ce1[e] = coef[row1 * E + e];
    }

    auto ld_B = [&](int s, float* r) {
        const int e = s % E, kb = kb0 + s / E;
        const float* src = w + ((size_t)e * IN_DIM + kb * 32 + tkq * 4) * H_DIM + colW;
        #pragma unroll
        for (int j = 0; j < 4; ++j) r[j] = src[(size_t)j * H_DIM];
    };
    auto ld_X = [&](int kb, float4* xr) {
        const float* p0 = x + (size_t)row0 * IN_DIM + kb * 32 + kq * 8;
        const float* p1 = x + (size_t)row1 * IN_DIM + kb * 32 + kq * 8;
        xr[0] = *reinterpret_cast<const float4*>(p0);
        xr[1] = *reinterpret_cast<const float4*>(p0 + 4);
        xr[2] = *reinterpret_cast<const float4*>(p1);
        xr[3] = *reinterpret_cast<const float4*>(p1 + 4);
    };

    f32x4 acc00 = {0.f,0.f,0.f,0.f}, acc01 = {0.f,0.f,0.f,0.f};
    f32x4 acc10 = {0.f,0.f,0.f,0.f}, acc11 = {0.f,0.f,0.f,0.f};

    float wreg[2][4];
    float4 xreg[2][4];
    ld_B(0, wreg[0]); ld_B(1, wreg[1]);
    ld_X(kb0, xreg[0]); ld_X(kb0 + 1, xreg[1]);

    #pragma unroll
    for (int s = 0; s < E * 4; ++s) {
        const int pb_ = s & 1, e = s % E, kbi = s / E;
        uint2 pk;
        pk.x = pk2(wreg[pb_][0], wreg[pb_][1]);
        pk.y = pk2(wreg[pb_][2], wreg[pb_][3]);
        *reinterpret_cast<uint2*>(&bs[pb_][fI][lp][j0]) = pk;

        const float4* xc = xreg[kbi & 1];
        U128 a0, a1;
        a0.us[0] = f2bf(xc[0].x * ce0[e]); a0.us[1] = f2bf(xc[0].y * ce0[e]);
        a0.us[2] = f2bf(xc[0].z * ce0[e]); a0.us[3] = f2bf(xc[0].w * ce0[e]);
        a0.us[4] = f2bf(xc[1].x * ce0[e]); a0.us[5] = f2bf(xc[1].y * ce0[e]);
        a0.us[6] = f2bf(xc[1].z * ce0[e]); a0.us[7] = f2bf(xc[1].w * ce0[e]);
        a1.us[0] = f2bf(xc[2].x * ce1[e]); a1.us[1] = f2bf(xc[2].y * ce1[e]);
        a1.us[2] = f2bf(xc[2].z * ce1[e]); a1.us[3] = f2bf(xc[2].w * ce1[e]);
        a1.us[4] = f2bf(xc[3].x * ce1[e]); a1.us[5] = f2bf(xc[3].y * ce1[e]);
        a1.us[6] = f2bf(xc[3].z * ce1[e]); a1.us[7] = f2bf(xc[3].w * ce1[e]);

        if (s + 2 < E * 4) ld_B(s + 2, wreg[pb_]);          // W prefetch
        if (e == E - 1 && kbi + 2 < 4)                      // x prefetch
            ld_X(kb0 + kbi + 2, xreg[kbi & 1]);

        __syncthreads();
        U128 b0, b1;
        b0.u4 = *reinterpret_cast<const uint4*>(&bs[pb_][0][l][0]);
        b1.u4 = *reinterpret_cast<const uint4*>(&bs[pb_][1][l][0]);
        acc00 = __builtin_amdgcn_mfma_f32_16x16x32_bf16(a0.s8, b0.s8, acc00, 0, 0, 0);
        acc01 = __builtin_amdgcn_mfma_f32_16x16x32_bf16(a0.s8, b1.s8, acc01, 0, 0, 0);
        acc10 = __builtin_amdgcn_mfma_f32_16x16x32_bf16(a1.s8, b0.s8, acc10, 0, 0, 0);
        acc11 = __builtin_amdgcn_mfma_f32_16x16x32_bf16(a1.s8, b1.s8, acc11, 0, 0, 0);
    }

    const int colB = n0 + (l & 15);
    const int rsub = (l >> 4) << 2;
    #pragma unroll
    for (int mi = 0; mi < 2; ++mi) {
        const int row = wv * 32 + mi * 16 + rsub;
        const f32x4 c0 = mi ? acc10 : acc00;
        const f32x4 c1 = mi ? acc11 : acc01;
        #pragma unroll
        for (int r = 0; r < 4; ++r) {
            atomicAdd(&y1[(size_t)(row + r) * H_DIM + colB],      c0[r]);
            atomicAdd(&y1[(size_t)(row + r) * H_DIM + colB + 16], c1[r]);
        }
    }
}

// ---------------------------------------------------------------------------
// gemm_mid: L2/L3. Prologue: O(1) loads — yin already holds accum+bias, so
// act = elu(yin) (or raw z for the z-split). Then the same MFMA pipeline;
// epilogue atomicAdds into yout (bias pre-initialized; ALWAYS workspace).
// ---------------------------------------------------------------------------
template<int KPB, bool ZS, int NW, bool GUARD>
__device__ __forceinline__ void gemm_mid_body(
    const float* __restrict__ yin,   // [B][H_DIM] accum(+bias) pre-ELU
    const float* __restrict__ coef,  // [B][E]
    const float* __restrict__ z,     // [B][ZD]
    const float* __restrict__ w,     // [E][K2][NW]
    float* __restrict__ yout,        // [B][NW] accum (workspace)
    int nt, int kb0, ushort (*bs)[2][64][8])
{
    constexpr int NS = E * KPB;
    const int tid = threadIdx.x;
    const int l = tid & 63, wv = tid >> 6;
    const int n0 = nt * 32;
    const int tn = tid & 31, tkq = tid >> 5;
    const int lp = ((tkq >> 1) << 4) | (tn & 15);
    const int fI = tn >> 4, j0 = (tkq & 1) << 2;
    const int colW = n0 + tn;
    const int row0 = 32 * wv + (l & 15), row1 = row0 + 16, kq = l >> 4;

    float ce0[E], ce1[E];
    #pragma unroll
    for (int e = 0; e < E; ++e) {
        ce0[e] = coef[row0 * E + e];
        ce1[e] = coef[row1 * E + e];
    }

    // ---- prologue: per-thread activations for this k-range (8 loads) ----
    float v0[KPB * 8], v1[KPB * 8];
    if (ZS) {
        const float4 za = *reinterpret_cast<const float4*>(z + row0 * ZD + kq * 8);
        const float4 zb = *reinterpret_cast<const float4*>(z + row0 * ZD + kq * 8 + 4);
        const float4 zc = *reinterpret_cast<const float4*>(z + row1 * ZD + kq * 8);
        const float4 zd = *reinterpret_cast<const float4*>(z + row1 * ZD + kq * 8 + 4);
        v0[0]=za.x; v0[1]=za.y; v0[2]=za.z; v0[3]=za.w;
        v0[4]=zb.x; v0[5]=zb.y; v0[6]=zb.z; v0[7]=zb.w;
        v1[0]=zc.x; v1[1]=zc.y; v1[2]=zc.z; v1[3]=zc.w;
        v1[4]=zd.x; v1[5]=zd.y; v1[6]=zd.z; v1[7]=zd.w;
    } else {
        #pragma unroll
        for (int kbi = 0; kbi < KPB; ++kbi) {
            const int kk = (kb0 + kbi) * 32 + kq * 8;
            const float* p0 = yin + (size_t)row0 * H_DIM + kk;
            const float* p1 = yin + (size_t)row1 * H_DIM + kk;
            const float4 a = *reinterpret_cast<const float4*>(p0);
            const float4 b = *reinterpret_cast<const float4*>(p0 + 4);
            const float4 c = *reinterpret_cast<const float4*>(p1);
            const float4 d = *reinterpret_cast<const float4*>(p1 + 4);
            v0[kbi*8+0]=elu1(a.x); v0[kbi*8+1]=elu1(a.y);
            v0[kbi*8+2]=elu1(a.z); v0[kbi*8+3]=elu1(a.w);
            v0[kbi*8+4]=elu1(b.x); v0[kbi*8+5]=elu1(b.y);
            v0[kbi*8+6]=elu1(b.z); v0[kbi*8+7]=elu1(b.w);
            v1[kbi*8+0]=elu1(c.x); v1[kbi*8+1]=elu1(c.y);
            v1[kbi*8+2]=elu1(c.z); v1[kbi*8+3]=elu1(c.w);
            v1[kbi*8+4]=elu1(d.x); v1[kbi*8+5]=elu1(d.y);
            v1[kbi*8+6]=elu1(d.z); v1[kbi*8+7]=elu1(d.w);
        }
    }

    // ---- MFMA pipeline ----
    auto ld_B = [&](int s, float* r) {
        const int e = s % E, kb = kb0 + s / E;
        const float* src = w + ((size_t)e * K2 + kb * 32 + tkq * 4) * NW + colW;
        #pragma unroll
        for (int j = 0; j < 4; ++j)
            r[j] = (!GUARD || colW < NW) ? src[(size_t)j * NW] : 0.f;
    };

    f32x4 acc00 = {0.f,0.f,0.f,0.f}, acc01 = {0.f,0.f,0.f,0.f};
    f32x4 acc10 = {0.f,0.f,0.f,0.f}, acc11 = {0.f,0.f,0.f,0.f};

    float wreg[2][4];
    ld_B(0, wreg[0]);
    if (NS > 1) ld_B(1, wreg[1]);

    #pragma unroll
    for (int s = 0; s < NS; ++s) {
        const int pb_ = s & 1, e = s % E, kbi = s / E;
        uint2 pk;
        pk.x = pk2(wreg[pb_][0], wreg[pb_][1]);
        pk.y = pk2(wreg[pb_][2], wreg[pb_][3]);
        *reinterpret_cast<uint2*>(&bs[pb_][fI][lp][j0]) = pk;

        U128 a0, a1;
        #pragma unroll
        for (int j = 0; j < 8; ++j) {
            a0.us[j] = f2bf(v0[kbi * 8 + j] * ce0[e]);
            a1.us[j] = f2bf(v1[kbi * 8 + j] * ce1[e]);
        }

        if (s + 2 < NS) ld_B(s + 2, wreg[pb_]);

        __syncthreads();
        U128 b0, b1;
        b0.u4 = *reinterpret_cast<const uint4*>(&bs[pb_][0][l][0]);
        b1.u4 = *reinterpret_cast<const uint4*>(&bs[pb_][1][l][0]);
        acc00 = __builtin_amdgcn_mfma_f32_16x16x32_bf16(a0.s8, b0.s8, acc00, 0, 0, 0);
        acc01 = __builtin_amdgcn_mfma_f32_16x16x32_bf16(a0.s8, b1.s8, acc01, 0, 0, 0);
        acc10 = __builtin_amdgcn_mfma_f32_16x16x32_bf16(a1.s8, b0.s8, acc10, 0, 0, 0);
        acc11 = __builtin_amdgcn_mfma_f32_16x16x32_bf16(a1.s8, b1.s8, acc11, 0, 0, 0);
    }

    const int colB = n0 + (l & 15);
    const int rsub = (l >> 4) << 2;
    #pragma unroll
    for (int mi = 0; mi < 2; ++mi) {
        const int row = wv * 32 + mi * 16 + rsub;
        const f32x4 c0 = mi ? acc10 : acc00;
        const f32x4 c1 = mi ? acc11 : acc01;
        #pragma unroll
        for (int r = 0; r < 4; ++r) {
            if (!GUARD || colB < NW)
                atomicAdd(&yout[(size_t)(row + r) * NW + colB], c0[r]);
            if (!GUARD || colB + 16 < NW)
                atomicAdd(&yout[(size_t)(row + r) * NW + colB + 16], c1[r]);
        }
    }
}

__global__ __launch_bounds__(256) void gemm_l2(
    const float* __restrict__ y1, const float* __restrict__ coef,
    const float* __restrict__ z, const float* __restrict__ w2,
    float* __restrict__ y2)
{
    __shared__ ushort bs[2][2][64][8];
    const int nt = blockIdx.x, sp = blockIdx.y;
    if (sp < 8)
        gemm_mid_body<2, false, H_DIM, false>(y1, coef, z, w2, y2, nt, sp * 2, bs);
    else
        gemm_mid_body<1, true, H_DIM, false>(y1, coef, z, w2, y2, nt, 16, bs);
}

__global__ __launch_bounds__(256) void gemm_l3(
    const float* __restrict__ y2, const float* __restrict__ coef,
    const float* __restrict__ z, const float* __restrict__ w3,
    float* __restrict__ y3)
{
    __shared__ ushort bs[2][2][64][8];
    const int nt = blockIdx.x, sp = blockIdx.y;
    if (sp < 8)
        gemm_mid_body<2, false, OUT_DIM, true>(y2, coef, z, w3, y3, nt, sp * 2, bs);
    else
        gemm_mid_body<1, true, OUT_DIM, true>(y2, coef, z, w3, y3, nt, 16, bs);
}

// fin_copy: y3 (ws accum, bias already included) -> d_out, plain float4 stores.
__global__ __launch_bounds__(256) void fin_copy(
    const float4* __restrict__ y3, float4* __restrict__ out)
{
    const int idx = blockIdx.x * 256 + threadIdx.x;
    if (idx < (B * OUT_DIM) / 4) out[idx] = y3[idx];
}

extern "C" void kernel_launch(void* const* d_in, const int* in_sizes, int n_in,
                              void* d_out, int out_size, void* d_ws, size_t ws_size,
                              hipStream_t stream)
{
    const float* p_prev = (const float*)d_in[0];
    const float* coef   = (const float*)d_in[1];
    const float* z      = (const float*)d_in[2];
    const float* w1     = (const float*)d_in[3];
    const float* b1     = (const float*)d_in[4];
    const float* w2     = (const float*)d_in[5];
    const float* b2     = (const float*)d_in[6];
    const float* w3     = (const float*)d_in[7];
    const float* b3     = (const float*)d_in[8];
    float* out = (float*)d_out;

    // ws: y1 | y2 | y3  (fp32 accumulators, re-initialized every call)
    float* y1 = (float*)d_ws;            // [B][512]
    float* y2 = y1 + (size_t)B * H_DIM;  // [B][512]
    float* y3 = y2 + (size_t)B * H_DIM;  // [B][618]

    const int TOT = B * (2 * H_DIM + OUT_DIM);
    init_bias<<<(TOT + 255) / 256, 256, 0, stream>>>(coef, b1, b2, b3, y1, y2, y3);
    gemm1<<<dim3(16, S1), 256, 0, stream>>>(p_prev, coef, w1, y1);
    gemm_l2<<<dim3(16, S23), 256, 0, stream>>>(y1, coef, z, w2, y2);
    gemm_l3<<<dim3(20, S23), 256, 0, stream>>>(y2, coef, z, w3, y3);
    fin_copy<<<(B * OUT_DIM / 4 + 255) / 256, 256, 0, stream>>>(
        (const float4*)y3, (float4*)out);
}